// Round 4
// baseline (292.482 us; speedup 1.0000x reference)
//
#include <hip/hip_runtime.h>
#include <hip/hip_bf16.h>

// IndRNNv2: 2 layers of { lin = x @ w^T + b ; h_s = relu(lin_s + r*h_{s-1}) }
// SEQ=256, BATCH=32, IN=HID=1024.
//
// bf16 hi/lo split GEMM on MFMA (3 terms: hiA*hiB + loA*hiB + hiA*loB),
// COMPACT storage: both operands stored [hi | lo] (K=2048 physical), the
// 96 logical K-steps remap: acol(kt) = kt&63, bcol(kt) = kt>=32 ? kt-32 : kt.
//
// R3->R4: occupancy was the GEMM wall (2 blocks/CU, 25% cap; MfmaUtil 29%).
// Split-K x2 -> 1024 blocks (4/CU), partial P0 = d_out y region, P1 = ws,
// reduction fused into the scan (which also adds bias now). Fallback to
// single-K if ws_size is too small. Splits fused into one kernel.

#define SEQ   256
#define BATCH 32
#define M_    (SEQ*BATCH)   // 8192
#define K_    1024
#define KC    2048          // compact split K (hi | lo)
#define KSTEP 96            // logical K-tiles of 32 (3 terms x 32)
#define N_    1024

typedef __attribute__((ext_vector_type(8))) short  short8;
typedef __attribute__((ext_vector_type(4))) float  floatx4;

// ---------------- fused f32 -> [hi | lo] bf16 split (x, w0, w1) -------------
// grid: [0,8192) -> x (2M vec4), [8192,9216) -> w0, [9216,10240) -> w1
__global__ __launch_bounds__(256) void split_all_k(
    const float* __restrict__ x,  __hip_bfloat16* __restrict__ dx,
    const float* __restrict__ w0, __hip_bfloat16* __restrict__ dw0,
    const float* __restrict__ w1, __hip_bfloat16* __restrict__ dw1)
{
    int bid = blockIdx.x;
    const float* src;
    __hip_bfloat16* dst;
    int t;
    if (bid < 8192)      { src = x;  dst = dx;  t = bid * 256 + threadIdx.x; }
    else if (bid < 9216) { src = w0; dst = dw0; t = (bid - 8192) * 256 + threadIdx.x; }
    else                 { src = w1; dst = dw1; t = (bid - 9216) * 256 + threadIdx.x; }

    int idx = t << 2;                       // 4 f32 per thread
    int row = idx >> 10, col = idx & 1023;  // source rows of 1024
    const float4 v = *reinterpret_cast<const float4*>(src + idx);
    float f[4] = {v.x, v.y, v.z, v.w};
    __hip_bfloat16 hi[4], lo[4];
#pragma unroll
    for (int i = 0; i < 4; ++i) {
        hi[i] = __float2bfloat16(f[i]);
        lo[i] = __float2bfloat16(f[i] - __bfloat162float(hi[i]));
    }
    size_t base = (size_t)row * KC + col;
    *reinterpret_cast<uint2*>(dst + base)        = *reinterpret_cast<const uint2*>(hi);
    *reinterpret_cast<uint2*>(dst + base + 1024) = *reinterpret_cast<const uint2*>(lo);
}

// ---------------- GEMM: P[m][n] = sum_kt A[m][acol]*B[n][bcol] ----------------
// m97-style: 128x128 tile, BK=32, 4 waves (2x2), 4x4 frags of 16x16x32 MFMA,
// global_load_lds width-16 staging, 2 barriers per K-step, XCD M-chunked
// swizzle. NSPLIT=2: h = bid>>9 selects K-half and partial buffer.
#define TM 128
#define TN 128
#define TK 32
#define NXCD 8
#define NTILES 512           // (M_/TM)*(N_/TN) = 64*8

template <int NSPLIT>
__global__ __launch_bounds__(256) void gemm_bt(
    const __hip_bfloat16* __restrict__ A,   // [M_][KC]
    const __hip_bfloat16* __restrict__ B,   // [N_][KC]
    float* __restrict__ P0,                 // [M_][N_] partial (h=0 / full)
    float* __restrict__ P1)                 // [M_][N_] partial (h=1)
{
    __shared__ __hip_bfloat16 As[TM * TK];
    __shared__ __hip_bfloat16 Bs[TN * TK];

    const int bid  = blockIdx.x;
    const int h    = (NSPLIT == 2) ? (bid >> 9) : 0;
    const int b512 = bid & (NTILES - 1);
    // XCD M-chunked swizzle: XCD k owns M-panels [8k,8k+8) x all 8 N-panels.
    // For NSPLIT=2 both halves of a tile land on the same XCD (bid%8 invariant).
    const int xcd  = b512 & (NXCD - 1);
    const int slot = b512 >> 3;
    const int tile = xcd * (NTILES / NXCD) + slot;
    const int ty   = tile >> 3;
    const int tx   = tile & 7;

    const int t    = threadIdx.x;
    const int lane = t & 63;
    const int wv   = t >> 6;
    const int wr   = wv >> 1;
    const int wc   = wv & 1;
    const int m0   = ty * TM;
    const int n0   = tx * TN;
    const int fr   = lane & 15;
    const int kb   = (lane >> 4) << 3;

    floatx4 acc[4][4] = {};

    const int kt0 = h * (KSTEP / NSPLIT);
    for (int it = 0; it < KSTEP / NSPLIT; ++it) {
        const int kt   = kt0 + it;
        const int acol = (kt & 63) * 32;                    // [hi|lo|hi] logical
        const int bcol = (kt >= 32 ? kt - 32 : kt) * 32;    // [hi|hi|lo] logical
        __syncthreads();   // prior iteration's ds_reads done before overwrite
#pragma unroll
        for (int i = 0; i < 2; ++i) {
            int chunk = wv * 128 + i * 64 + lane;    // 0..511, 16B each
            int row = chunk >> 2;
            int c8  = (chunk & 3) << 3;
            __builtin_amdgcn_global_load_lds(
                (__attribute__((address_space(1))) void*)(A + (size_t)(m0 + row) * KC + acol + c8),
                (__attribute__((address_space(3))) void*)(&As[chunk * 8]), 16, 0, 0);
            __builtin_amdgcn_global_load_lds(
                (__attribute__((address_space(1))) void*)(B + (size_t)(n0 + row) * KC + bcol + c8),
                (__attribute__((address_space(3))) void*)(&Bs[chunk * 8]), 16, 0, 0);
        }
        __syncthreads();   // compiler drains vmcnt before barrier

        short8 af[4], bf[4];
#pragma unroll
        for (int i = 0; i < 4; ++i)
            af[i] = *reinterpret_cast<const short8*>(&As[(wr * 64 + i * 16 + fr) * TK + kb]);
#pragma unroll
        for (int j = 0; j < 4; ++j)
            bf[j] = *reinterpret_cast<const short8*>(&Bs[(wc * 64 + j * 16 + fr) * TK + kb]);
#pragma unroll
        for (int i = 0; i < 4; ++i)
#pragma unroll
            for (int j = 0; j < 4; ++j)
                acc[i][j] = __builtin_amdgcn_mfma_f32_16x16x32_bf16(af[i], bf[j], acc[i][j], 0, 0, 0);
    }

    float* __restrict__ P = (h == 0) ? P0 : P1;
    // C/D layout (16x16): col = lane&15, row = (lane>>4)*4 + reg
#pragma unroll
    for (int j = 0; j < 4; ++j) {
        const int col = n0 + wc * 64 + j * 16 + fr;
#pragma unroll
        for (int i = 0; i < 4; ++i) {
            const int row = m0 + wr * 64 + i * 16 + ((lane >> 4) << 2);
#pragma unroll
            for (int jj = 0; jj < 4; ++jj)
                P[(size_t)(row + jj) * N_ + col] = acc[i][j][jj];
        }
    }
}

// ---------------- sequential scan over S (fused split-K reduce + bias) ------
// l = p0 + (SPLIT2 ? p1 : 0) + bias. LAYER==0: emit compact [hi|lo] split
// activations + h0T. LAYER==1: write y1 into yout + h1T.
template <int LAYER, bool SPLIT2>
__global__ __launch_bounds__(64) void scan_k(
    const float* __restrict__ p0,            // [SEQ][BATCH][N_]
    const float* __restrict__ p1,            // [SEQ][BATCH][N_] (SPLIT2)
    const float* __restrict__ bias,          // [N_]
    const float* __restrict__ rec,           // [2][N_]
    __hip_bfloat16* __restrict__ asplit,     // LAYER==0: [M_][KC]
    float* __restrict__ yout,                // LAYER==1: [SEQ][BATCH][N_]
    float* __restrict__ hT)                  // [BATCH][2*N_]
{
    const int tid = blockIdx.x * 64 + threadIdx.x;   // 0..32767
    const int b = tid >> 10, n = tid & 1023;
    const float r  = rec[LAYER * N_ + n];
    const float bj = bias[n];
    float h = 0.f;
#pragma unroll 8
    for (int s = 0; s < SEQ; ++s) {
        const size_t i = (size_t)s * (BATCH * N_) + tid;
        float l = p0[i] + bj;
        if (SPLIT2) l += p1[i];
        h = fmaxf(fmaf(r, h, l), 0.f);
        if (LAYER == 0) {
            size_t base = (size_t)(s * BATCH + b) * KC + n;
            __hip_bfloat16 hi = __float2bfloat16(h);
            __hip_bfloat16 lo = __float2bfloat16(h - __bfloat162float(hi));
            asplit[base]        = hi;   // compact [hi | lo]
            asplit[base + 1024] = lo;
        } else {
            yout[i] = h;
        }
    }
    hT[(size_t)b * (2 * N_) + LAYER * N_ + n] = h;
}

// ---------------- launch ----------------
extern "C" void kernel_launch(void* const* d_in, const int* in_sizes, int n_in,
                              void* d_out, int out_size, void* d_ws, size_t ws_size,
                              hipStream_t stream)
{
    const float* x   = (const float*)d_in[0];
    const float* w0  = (const float*)d_in[1];
    const float* b0  = (const float*)d_in[2];
    const float* w1  = (const float*)d_in[3];
    const float* b1  = (const float*)d_in[4];
    const float* rec = (const float*)d_in[5];

    float* out = (float*)d_out;
    float* y   = out;                               // [SEQ][BATCH][N_] — P0 scratch then final y1
    float* hT  = out + (size_t)SEQ * BATCH * N_;    // [BATCH][2*N_]

    // ws layout (compact): A0 33.55 MB | W0 4.19 | W1 4.19 | P1 33.55 (f32)
    __hip_bfloat16* A0 = (__hip_bfloat16*)d_ws;
    __hip_bfloat16* W0 = A0 + (size_t)M_ * KC;
    __hip_bfloat16* W1 = W0 + (size_t)N_ * KC;
    float*          P1 = (float*)(W1 + (size_t)N_ * KC);
    const size_t need = (size_t)M_ * KC * 2 + 2 * (size_t)N_ * KC * 2
                      + (size_t)M_ * N_ * 4;        // 75,497,472 B
    const bool deep = ws_size >= need;              // split-K x2 if ws allows

    // 1. split x, w0, w1 -> compact [hi|lo] bf16 (one kernel)
    split_all_k<<<10240, 256, 0, stream>>>(x, A0, w0, W0, w1, W1);

    if (deep) {
        // 2. lin0 partials
        gemm_bt<2><<<2 * NTILES, 256, 0, stream>>>(A0, W0, y, P1);
        // 3. scan layer 0 (reduce p0+p1+b0) -> compact split acts + h0T
        scan_k<0, true><<<(BATCH * N_) / 64, 64, 0, stream>>>(y, P1, b0, rec, A0, nullptr, hT);
        // 4. lin1 partials
        gemm_bt<2><<<2 * NTILES, 256, 0, stream>>>(A0, W1, y, P1);
        // 5. scan layer 1 -> y1 + h1T
        scan_k<1, true><<<(BATCH * N_) / 64, 64, 0, stream>>>(y, P1, b1, rec, nullptr, y, hT);
    } else {
        gemm_bt<1><<<NTILES, 256, 0, stream>>>(A0, W0, y, nullptr);
        scan_k<0, false><<<(BATCH * N_) / 64, 64, 0, stream>>>(y, nullptr, b0, rec, A0, nullptr, hT);
        gemm_bt<1><<<NTILES, 256, 0, stream>>>(A0, W1, y, nullptr);
        scan_k<1, false><<<(BATCH * N_) / 64, 64, 0, stream>>>(y, nullptr, b1, rec, nullptr, y, hT);
    }
}

// Round 5
// 228.591 us; speedup vs baseline: 1.2795x; 1.2795x over previous
//
#include <hip/hip_runtime.h>
#include <hip/hip_bf16.h>

// IndRNNv2: 2 layers of { lin = x @ w^T + b ; h_s = relu(lin_s + r*h_{s-1}) }
// SEQ=256, BATCH=32, IN=HID=1024.
//
// bf16 hi/lo split GEMM on MFMA, 3 terms: C = Ahi*Bhi + Alo*Bhi + Ahi*Blo.
// Compact storage [hi | lo] (K=2048 physical) for both operands.
//
// R4->R5: GEMM is staging-BW-bound (~40 GB/s/CU global_load_lds; split-K
// doubled co-resident staging and per-step time doubled). Merge the 3 terms
// into ONE K-loop that stages {Ahi, Alo, Bhi, Blo} (32 KB) per step and
// fires 48 MFMA/wave: staged bytes -33%, barriers -33%, same sync template.
// Split-K reverted; scan unroll 16.

#define SEQ   256
#define BATCH 32
#define M_    (SEQ*BATCH)   // 8192
#define K_    1024
#define KC    2048          // compact split K (hi | lo)
#define N_    1024

typedef __attribute__((ext_vector_type(8))) short  short8;
typedef __attribute__((ext_vector_type(4))) float  floatx4;

// ---------------- fused f32 -> [hi | lo] bf16 split (x, w0, w1) -------------
// grid: [0,8192) -> x, [8192,9216) -> w0, [9216,10240) -> w1
__global__ __launch_bounds__(256) void split_all_k(
    const float* __restrict__ x,  __hip_bfloat16* __restrict__ dx,
    const float* __restrict__ w0, __hip_bfloat16* __restrict__ dw0,
    const float* __restrict__ w1, __hip_bfloat16* __restrict__ dw1)
{
    int bid = blockIdx.x;
    const float* src;
    __hip_bfloat16* dst;
    int t;
    if (bid < 8192)      { src = x;  dst = dx;  t = bid * 256 + threadIdx.x; }
    else if (bid < 9216) { src = w0; dst = dw0; t = (bid - 8192) * 256 + threadIdx.x; }
    else                 { src = w1; dst = dw1; t = (bid - 9216) * 256 + threadIdx.x; }

    int idx = t << 2;                       // 4 f32 per thread
    int row = idx >> 10, col = idx & 1023;  // source rows of 1024
    const float4 v = *reinterpret_cast<const float4*>(src + idx);
    float f[4] = {v.x, v.y, v.z, v.w};
    __hip_bfloat16 hi[4], lo[4];
#pragma unroll
    for (int i = 0; i < 4; ++i) {
        hi[i] = __float2bfloat16(f[i]);
        lo[i] = __float2bfloat16(f[i] - __bfloat162float(hi[i]));
    }
    size_t base = (size_t)row * KC + col;
    *reinterpret_cast<uint2*>(dst + base)        = *reinterpret_cast<const uint2*>(hi);
    *reinterpret_cast<uint2*>(dst + base + 1024) = *reinterpret_cast<const uint2*>(lo);
}

// ---------------- GEMM: P[m][n] = sum over 3 split terms ----------------
// 128x128 tile, BK=32, 4 waves (2x2), per step stage 4 tiles (Ahi/Alo/Bhi/Blo,
// 32 KB) then 48 MFMA/wave (3 terms x 4x4 frags). 2 barriers per step,
// 32 steps. XCD M-chunked swizzle.
#define TM 128
#define TN 128
#define TK 32
#define NXCD 8
#define NTILES 512           // (M_/TM)*(N_/TN) = 64*8

__global__ __launch_bounds__(256) void gemm_bt(
    const __hip_bfloat16* __restrict__ A,   // [M_][KC]
    const __hip_bfloat16* __restrict__ B,   // [N_][KC]
    float* __restrict__ P)                  // [M_][N_]
{
    __shared__ __hip_bfloat16 Ah[TM * TK];  // 8 KB each
    __shared__ __hip_bfloat16 Al[TM * TK];
    __shared__ __hip_bfloat16 Bh[TN * TK];
    __shared__ __hip_bfloat16 Bl[TN * TK];

    // XCD M-chunked swizzle: XCD k owns M-panels [8k,8k+8) x all 8 N-panels.
    const int bid  = blockIdx.x;
    const int xcd  = bid & (NXCD - 1);
    const int slot = bid >> 3;
    const int tile = xcd * (NTILES / NXCD) + slot;
    const int ty   = tile >> 3;
    const int tx   = tile & 7;

    const int t    = threadIdx.x;
    const int lane = t & 63;
    const int wv   = t >> 6;
    const int wr   = wv >> 1;
    const int wc   = wv & 1;
    const int m0   = ty * TM;
    const int n0   = tx * TN;
    const int fr   = lane & 15;
    const int kb   = (lane >> 4) << 3;

    floatx4 acc[4][4] = {};

    for (int kt = 0; kt < K_ / TK; ++kt) {     // 32 steps
        const int hi0 = kt * TK;               // hi cols
        const int lo0 = 1024 + kt * TK;        // lo cols
        __syncthreads();   // prior iteration's ds_reads done before overwrite
#pragma unroll
        for (int i = 0; i < 2; ++i) {
            const int chunk = i * 256 + t;     // 0..511, 16B each
            const int row = chunk >> 2;
            const int c8  = (chunk & 3) << 3;
            const size_t arow = (size_t)(m0 + row) * KC;
            const size_t brow = (size_t)(n0 + row) * KC;
            __builtin_amdgcn_global_load_lds(
                (__attribute__((address_space(1))) void*)(A + arow + hi0 + c8),
                (__attribute__((address_space(3))) void*)(&Ah[chunk * 8]), 16, 0, 0);
            __builtin_amdgcn_global_load_lds(
                (__attribute__((address_space(1))) void*)(A + arow + lo0 + c8),
                (__attribute__((address_space(3))) void*)(&Al[chunk * 8]), 16, 0, 0);
            __builtin_amdgcn_global_load_lds(
                (__attribute__((address_space(1))) void*)(B + brow + hi0 + c8),
                (__attribute__((address_space(3))) void*)(&Bh[chunk * 8]), 16, 0, 0);
            __builtin_amdgcn_global_load_lds(
                (__attribute__((address_space(1))) void*)(B + brow + lo0 + c8),
                (__attribute__((address_space(3))) void*)(&Bl[chunk * 8]), 16, 0, 0);
        }
        __syncthreads();   // compiler drains vmcnt before barrier

        short8 afh[4], afl[4], bfh[4], bfl[4];
#pragma unroll
        for (int i = 0; i < 4; ++i) {
            const int ar = (wr * 64 + i * 16 + fr) * TK + kb;
            afh[i] = *reinterpret_cast<const short8*>(&Ah[ar]);
            afl[i] = *reinterpret_cast<const short8*>(&Al[ar]);
        }
#pragma unroll
        for (int j = 0; j < 4; ++j) {
            const int br = (wc * 64 + j * 16 + fr) * TK + kb;
            bfh[j] = *reinterpret_cast<const short8*>(&Bh[br]);
            bfl[j] = *reinterpret_cast<const short8*>(&Bl[br]);
        }
#pragma unroll
        for (int i = 0; i < 4; ++i)
#pragma unroll
            for (int j = 0; j < 4; ++j) {
                acc[i][j] = __builtin_amdgcn_mfma_f32_16x16x32_bf16(afh[i], bfh[j], acc[i][j], 0, 0, 0);
                acc[i][j] = __builtin_amdgcn_mfma_f32_16x16x32_bf16(afl[i], bfh[j], acc[i][j], 0, 0, 0);
                acc[i][j] = __builtin_amdgcn_mfma_f32_16x16x32_bf16(afh[i], bfl[j], acc[i][j], 0, 0, 0);
            }
    }

    // epilogue: C/D layout (16x16): col = lane&15, row = (lane>>4)*4 + reg
#pragma unroll
    for (int j = 0; j < 4; ++j) {
        const int col = n0 + wc * 64 + j * 16 + fr;
#pragma unroll
        for (int i = 0; i < 4; ++i) {
            const int row = m0 + wr * 64 + i * 16 + ((lane >> 4) << 2);
#pragma unroll
            for (int jj = 0; jj < 4; ++jj)
                P[(size_t)(row + jj) * N_ + col] = acc[i][j][jj];
        }
    }
}

// ---------------- sequential scan over S (adds bias) ----------------
// LAYER==0: emit compact [hi|lo] split activations + h0T.
// LAYER==1: write y1 into yout + h1T.
template <int LAYER>
__global__ __launch_bounds__(64) void scan_k(
    const float* __restrict__ p0,            // [SEQ][BATCH][N_]
    const float* __restrict__ bias,          // [N_]
    const float* __restrict__ rec,           // [2][N_]
    __hip_bfloat16* __restrict__ asplit,     // LAYER==0: [M_][KC]
    float* __restrict__ yout,                // LAYER==1: [SEQ][BATCH][N_]
    float* __restrict__ hT)                  // [BATCH][2*N_]
{
    const int tid = blockIdx.x * 64 + threadIdx.x;   // 0..32767
    const int b = tid >> 10, n = tid & 1023;
    const float r  = rec[LAYER * N_ + n];
    const float bj = bias[n];
    float h = 0.f;
#pragma unroll 16
    for (int s = 0; s < SEQ; ++s) {
        const size_t i = (size_t)s * (BATCH * N_) + tid;
        float l = p0[i] + bj;
        h = fmaxf(fmaf(r, h, l), 0.f);
        if (LAYER == 0) {
            size_t base = (size_t)(s * BATCH + b) * KC + n;
            __hip_bfloat16 hi = __float2bfloat16(h);
            __hip_bfloat16 lo = __float2bfloat16(h - __bfloat162float(hi));
            asplit[base]        = hi;   // compact [hi | lo]
            asplit[base + 1024] = lo;
        } else {
            yout[i] = h;
        }
    }
    hT[(size_t)b * (2 * N_) + LAYER * N_ + n] = h;
}

// ---------------- launch ----------------
extern "C" void kernel_launch(void* const* d_in, const int* in_sizes, int n_in,
                              void* d_out, int out_size, void* d_ws, size_t ws_size,
                              hipStream_t stream)
{
    const float* x   = (const float*)d_in[0];
    const float* w0  = (const float*)d_in[1];
    const float* b0  = (const float*)d_in[2];
    const float* w1  = (const float*)d_in[3];
    const float* b1  = (const float*)d_in[4];
    const float* rec = (const float*)d_in[5];

    float* out = (float*)d_out;
    float* y   = out;                               // [SEQ][BATCH][N_] — lin scratch then final y1
    float* hT  = out + (size_t)SEQ * BATCH * N_;    // [BATCH][2*N_]

    // ws layout: A0 33.55 MB | W0 4.19 MB | W1 4.19 MB  (~42 MB, ws proven >= 63 MB)
    __hip_bfloat16* A0 = (__hip_bfloat16*)d_ws;
    __hip_bfloat16* W0 = A0 + (size_t)M_ * KC;
    __hip_bfloat16* W1 = W0 + (size_t)N_ * KC;

    // 1. split x, w0, w1 -> compact [hi|lo] bf16 (one kernel)
    split_all_k<<<10240, 256, 0, stream>>>(x, A0, w0, W0, w1, W1);

    // 2. lin0 = x @ w0^T   (bias added in scan)
    gemm_bt<<<NTILES, 256, 0, stream>>>(A0, W0, y);

    // 3. scan layer 0 -> compact split acts (reuse A0) + h0T
    scan_k<0><<<(BATCH * N_) / 64, 64, 0, stream>>>(y, b0, rec, A0, nullptr, hT);

    // 4. lin1 = y0 @ w1^T
    gemm_bt<<<NTILES, 256, 0, stream>>>(A0, W1, y);

    // 5. scan layer 1 -> y1 (in place) + h1T
    scan_k<1><<<(BATCH * N_) / 64, 64, 0, stream>>>(y, b1, rec, nullptr, y, hT);
}

// Round 6
// 226.956 us; speedup vs baseline: 1.2887x; 1.0072x over previous
//
#include <hip/hip_runtime.h>
#include <hip/hip_bf16.h>

// IndRNNv2: 2 layers of { lin = x @ w^T + b ; h_s = relu(lin_s + r*h_{s-1}) }
// SEQ=256, BATCH=32, IN=HID=1024.
//
// bf16 hi/lo split GEMM on MFMA, 3 terms: C = Ahi*Bhi + Alo*Bhi + Ahi*Blo.
// Compact storage [hi | lo] (K=2048 physical) for both operands.
// GEMM: term-merged staging (R5), at the m97 128x128-structure ceiling
// (862 TF measured vs 874-912 reference).
//
// R5->R6: scans were ~47us each vs ~11us BW floor (2 waves/CU, loads
// serialized at full memory latency -- unroll pragma didn't batch them).
// Rewrite scan with an explicit software pipeline: prefetch the next
// 16-step batch into registers while processing the current one (T14
// issue-early/consume-late). Also removes layer-1 restrict aliasing UB.

#define SEQ   256
#define BATCH 32
#define M_    (SEQ*BATCH)   // 8192
#define K_    1024
#define KC    2048          // compact split K (hi | lo)
#define N_    1024

typedef __attribute__((ext_vector_type(8))) short  short8;
typedef __attribute__((ext_vector_type(4))) float  floatx4;

// ---------------- fused f32 -> [hi | lo] bf16 split (x, w0, w1) -------------
// grid: [0,8192) -> x, [8192,9216) -> w0, [9216,10240) -> w1
__global__ __launch_bounds__(256) void split_all_k(
    const float* __restrict__ x,  __hip_bfloat16* __restrict__ dx,
    const float* __restrict__ w0, __hip_bfloat16* __restrict__ dw0,
    const float* __restrict__ w1, __hip_bfloat16* __restrict__ dw1)
{
    int bid = blockIdx.x;
    const float* src;
    __hip_bfloat16* dst;
    int t;
    if (bid < 8192)      { src = x;  dst = dx;  t = bid * 256 + threadIdx.x; }
    else if (bid < 9216) { src = w0; dst = dw0; t = (bid - 8192) * 256 + threadIdx.x; }
    else                 { src = w1; dst = dw1; t = (bid - 9216) * 256 + threadIdx.x; }

    int idx = t << 2;                       // 4 f32 per thread
    int row = idx >> 10, col = idx & 1023;  // source rows of 1024
    const float4 v = *reinterpret_cast<const float4*>(src + idx);
    float f[4] = {v.x, v.y, v.z, v.w};
    __hip_bfloat16 hi[4], lo[4];
#pragma unroll
    for (int i = 0; i < 4; ++i) {
        hi[i] = __float2bfloat16(f[i]);
        lo[i] = __float2bfloat16(f[i] - __bfloat162float(hi[i]));
    }
    size_t base = (size_t)row * KC + col;
    *reinterpret_cast<uint2*>(dst + base)        = *reinterpret_cast<const uint2*>(hi);
    *reinterpret_cast<uint2*>(dst + base + 1024) = *reinterpret_cast<const uint2*>(lo);
}

// ---------------- GEMM: P[m][n] = sum over 3 split terms ----------------
// 128x128 tile, BK=32, 4 waves (2x2), per step stage 4 tiles (Ahi/Alo/Bhi/Blo,
// 32 KB) then 48 MFMA/wave (3 terms x 4x4 frags). 2 barriers per step,
// 32 steps. XCD M-chunked swizzle.
#define TM 128
#define TN 128
#define TK 32
#define NXCD 8
#define NTILES 512           // (M_/TM)*(N_/TN) = 64*8

__global__ __launch_bounds__(256) void gemm_bt(
    const __hip_bfloat16* __restrict__ A,   // [M_][KC]
    const __hip_bfloat16* __restrict__ B,   // [N_][KC]
    float* __restrict__ P)                  // [M_][N_]
{
    __shared__ __hip_bfloat16 Ah[TM * TK];  // 8 KB each
    __shared__ __hip_bfloat16 Al[TM * TK];
    __shared__ __hip_bfloat16 Bh[TN * TK];
    __shared__ __hip_bfloat16 Bl[TN * TK];

    // XCD M-chunked swizzle: XCD k owns M-panels [8k,8k+8) x all 8 N-panels.
    const int bid  = blockIdx.x;
    const int xcd  = bid & (NXCD - 1);
    const int slot = bid >> 3;
    const int tile = xcd * (NTILES / NXCD) + slot;
    const int ty   = tile >> 3;
    const int tx   = tile & 7;

    const int t    = threadIdx.x;
    const int lane = t & 63;
    const int wv   = t >> 6;
    const int wr   = wv >> 1;
    const int wc   = wv & 1;
    const int m0   = ty * TM;
    const int n0   = tx * TN;
    const int fr   = lane & 15;
    const int kb   = (lane >> 4) << 3;

    floatx4 acc[4][4] = {};

    for (int kt = 0; kt < K_ / TK; ++kt) {     // 32 steps
        const int hi0 = kt * TK;               // hi cols
        const int lo0 = 1024 + kt * TK;        // lo cols
        __syncthreads();   // prior iteration's ds_reads done before overwrite
#pragma unroll
        for (int i = 0; i < 2; ++i) {
            const int chunk = i * 256 + t;     // 0..511, 16B each
            const int row = chunk >> 2;
            const int c8  = (chunk & 3) << 3;
            const size_t arow = (size_t)(m0 + row) * KC;
            const size_t brow = (size_t)(n0 + row) * KC;
            __builtin_amdgcn_global_load_lds(
                (__attribute__((address_space(1))) void*)(A + arow + hi0 + c8),
                (__attribute__((address_space(3))) void*)(&Ah[chunk * 8]), 16, 0, 0);
            __builtin_amdgcn_global_load_lds(
                (__attribute__((address_space(1))) void*)(A + arow + lo0 + c8),
                (__attribute__((address_space(3))) void*)(&Al[chunk * 8]), 16, 0, 0);
            __builtin_amdgcn_global_load_lds(
                (__attribute__((address_space(1))) void*)(B + brow + hi0 + c8),
                (__attribute__((address_space(3))) void*)(&Bh[chunk * 8]), 16, 0, 0);
            __builtin_amdgcn_global_load_lds(
                (__attribute__((address_space(1))) void*)(B + brow + lo0 + c8),
                (__attribute__((address_space(3))) void*)(&Bl[chunk * 8]), 16, 0, 0);
        }
        __syncthreads();   // compiler drains vmcnt before barrier

        short8 afh[4], afl[4], bfh[4], bfl[4];
#pragma unroll
        for (int i = 0; i < 4; ++i) {
            const int ar = (wr * 64 + i * 16 + fr) * TK + kb;
            afh[i] = *reinterpret_cast<const short8*>(&Ah[ar]);
            afl[i] = *reinterpret_cast<const short8*>(&Al[ar]);
        }
#pragma unroll
        for (int j = 0; j < 4; ++j) {
            const int br = (wc * 64 + j * 16 + fr) * TK + kb;
            bfh[j] = *reinterpret_cast<const short8*>(&Bh[br]);
            bfl[j] = *reinterpret_cast<const short8*>(&Bl[br]);
        }
#pragma unroll
        for (int i = 0; i < 4; ++i)
#pragma unroll
            for (int j = 0; j < 4; ++j) {
                acc[i][j] = __builtin_amdgcn_mfma_f32_16x16x32_bf16(afh[i], bfh[j], acc[i][j], 0, 0, 0);
                acc[i][j] = __builtin_amdgcn_mfma_f32_16x16x32_bf16(afl[i], bfh[j], acc[i][j], 0, 0, 0);
                acc[i][j] = __builtin_amdgcn_mfma_f32_16x16x32_bf16(afh[i], bfl[j], acc[i][j], 0, 0, 0);
            }
    }

    // epilogue: C/D layout (16x16): col = lane&15, row = (lane>>4)*4 + reg
#pragma unroll
    for (int j = 0; j < 4; ++j) {
        const int col = n0 + wc * 64 + j * 16 + fr;
#pragma unroll
        for (int i = 0; i < 4; ++i) {
            const int row = m0 + wr * 64 + i * 16 + ((lane >> 4) << 2);
#pragma unroll
            for (int jj = 0; jj < 4; ++jj)
                P[(size_t)(row + jj) * N_ + col] = acc[i][j][jj];
        }
    }
}

// ---------------- sequential scan over S (adds bias) ----------------
// Software-pipelined: prefetch the next NB-step batch of lin into registers
// while processing the current batch. LAYER==0: emit compact [hi|lo] split
// activations + h0T. LAYER==1: rewrite lin in place with y1 + h1T.
#define NB 16

template <int LAYER>
__global__ __launch_bounds__(64) void scan_k(
    float* lin,                              // [SEQ][BATCH][N_]; LAYER==1: also output
    const float* __restrict__ bias,          // [N_]
    const float* __restrict__ rec,           // [2][N_]
    __hip_bfloat16* __restrict__ asplit,     // LAYER==0: [M_][KC]
    float* __restrict__ hT)                  // [BATCH][2*N_]
{
    const int tid = blockIdx.x * 64 + threadIdx.x;   // 0..32767
    const int b = tid >> 10, n = tid & 1023;
    const float r  = rec[LAYER * N_ + n];
    const float bj = bias[n];
    float h = 0.f;

    float v[NB], vn[NB];
#pragma unroll
    for (int j = 0; j < NB; ++j)
        v[j] = lin[(size_t)j * (BATCH * N_) + tid];

    for (int sb = 0; sb < SEQ / NB; ++sb) {
        const int sbase = sb * NB;
        if (sb + 1 < SEQ / NB) {
#pragma unroll
            for (int j = 0; j < NB; ++j)
                vn[j] = lin[(size_t)(sbase + NB + j) * (BATCH * N_) + tid];
        }
#pragma unroll
        for (int j = 0; j < NB; ++j) {
            h = fmaxf(fmaf(r, h, v[j] + bj), 0.f);
            if (LAYER == 0) {
                const size_t base = (size_t)((sbase + j) * BATCH + b) * KC + n;
                __hip_bfloat16 hi = __float2bfloat16(h);
                __hip_bfloat16 lo = __float2bfloat16(h - __bfloat162float(hi));
                asplit[base]        = hi;   // compact [hi | lo]
                asplit[base + 1024] = lo;
            } else {
                lin[(size_t)(sbase + j) * (BATCH * N_) + tid] = h;
            }
        }
#pragma unroll
        for (int j = 0; j < NB; ++j) v[j] = vn[j];
    }
    hT[(size_t)b * (2 * N_) + LAYER * N_ + n] = h;
}

// ---------------- launch ----------------
extern "C" void kernel_launch(void* const* d_in, const int* in_sizes, int n_in,
                              void* d_out, int out_size, void* d_ws, size_t ws_size,
                              hipStream_t stream)
{
    const float* x   = (const float*)d_in[0];
    const float* w0  = (const float*)d_in[1];
    const float* b0  = (const float*)d_in[2];
    const float* w1  = (const float*)d_in[3];
    const float* b1  = (const float*)d_in[4];
    const float* rec = (const float*)d_in[5];

    float* out = (float*)d_out;
    float* y   = out;                               // [SEQ][BATCH][N_] — lin scratch then final y1
    float* hT  = out + (size_t)SEQ * BATCH * N_;    // [BATCH][2*N_]

    // ws layout: A0 33.55 MB | W0 4.19 MB | W1 4.19 MB  (~42 MB, ws proven >= 63 MB)
    __hip_bfloat16* A0 = (__hip_bfloat16*)d_ws;
    __hip_bfloat16* W0 = A0 + (size_t)M_ * KC;
    __hip_bfloat16* W1 = W0 + (size_t)N_ * KC;

    // 1. split x, w0, w1 -> compact [hi|lo] bf16 (one kernel)
    split_all_k<<<10240, 256, 0, stream>>>(x, A0, w0, W0, w1, W1);

    // 2. lin0 = x @ w0^T   (bias added in scan)
    gemm_bt<<<NTILES, 256, 0, stream>>>(A0, W0, y);

    // 3. scan layer 0 -> compact split acts (reuse A0) + h0T
    scan_k<0><<<(BATCH * N_) / 64, 64, 0, stream>>>(y, b0, rec, A0, hT);

    // 4. lin1 = y0 @ w1^T
    gemm_bt<<<NTILES, 256, 0, stream>>>(A0, W1, y);

    // 5. scan layer 1 -> y1 (in place) + h1T
    scan_k<1><<<(BATCH * N_) / 64, 64, 0, stream>>>(y, b1, rec, nullptr, hT);
}

// Round 7
// 226.142 us; speedup vs baseline: 1.2934x; 1.0036x over previous
//
#include <hip/hip_runtime.h>
#include <hip/hip_bf16.h>

// IndRNNv2: 2 layers of { lin = x @ w^T + b ; h_s = relu(lin_s + r*h_{s-1}) }
// SEQ=256, BATCH=32, IN=HID=1024.
//
// bf16 hi/lo split GEMM on MFMA, 3 terms: C = Ahi*Bhi + Alo*Bhi + Ahi*Blo.
// Compact storage [hi | lo] (K=2048 physical) for both operands.
// GEMM: term-merged staging (R5), at the m97 128x128-structure ceiling
// (862 TF measured vs 874-912 reference).
//
// R6->R7: scans stream at only ~2.1 TB/s. In-flight-bytes analysis: the
// NB=16 register pipeline holds 32768 thr x 16 x 4B = 2 MB in flight, but
// the BW-latency product at ~600ns is ~3.8 MB -> pipeline depth, not the
// pipeline itself, was the limit. NB 16 -> 32 (4 MB in flight).

#define SEQ   256
#define BATCH 32
#define M_    (SEQ*BATCH)   // 8192
#define K_    1024
#define KC    2048          // compact split K (hi | lo)
#define N_    1024

typedef __attribute__((ext_vector_type(8))) short  short8;
typedef __attribute__((ext_vector_type(4))) float  floatx4;

// ---------------- fused f32 -> [hi | lo] bf16 split (x, w0, w1) -------------
// grid: [0,8192) -> x, [8192,9216) -> w0, [9216,10240) -> w1
__global__ __launch_bounds__(256) void split_all_k(
    const float* __restrict__ x,  __hip_bfloat16* __restrict__ dx,
    const float* __restrict__ w0, __hip_bfloat16* __restrict__ dw0,
    const float* __restrict__ w1, __hip_bfloat16* __restrict__ dw1)
{
    int bid = blockIdx.x;
    const float* src;
    __hip_bfloat16* dst;
    int t;
    if (bid < 8192)      { src = x;  dst = dx;  t = bid * 256 + threadIdx.x; }
    else if (bid < 9216) { src = w0; dst = dw0; t = (bid - 8192) * 256 + threadIdx.x; }
    else                 { src = w1; dst = dw1; t = (bid - 9216) * 256 + threadIdx.x; }

    int idx = t << 2;                       // 4 f32 per thread
    int row = idx >> 10, col = idx & 1023;  // source rows of 1024
    const float4 v = *reinterpret_cast<const float4*>(src + idx);
    float f[4] = {v.x, v.y, v.z, v.w};
    __hip_bfloat16 hi[4], lo[4];
#pragma unroll
    for (int i = 0; i < 4; ++i) {
        hi[i] = __float2bfloat16(f[i]);
        lo[i] = __float2bfloat16(f[i] - __bfloat162float(hi[i]));
    }
    size_t base = (size_t)row * KC + col;
    *reinterpret_cast<uint2*>(dst + base)        = *reinterpret_cast<const uint2*>(hi);
    *reinterpret_cast<uint2*>(dst + base + 1024) = *reinterpret_cast<const uint2*>(lo);
}

// ---------------- GEMM: P[m][n] = sum over 3 split terms ----------------
// 128x128 tile, BK=32, 4 waves (2x2), per step stage 4 tiles (Ahi/Alo/Bhi/Blo,
// 32 KB) then 48 MFMA/wave (3 terms x 4x4 frags). 2 barriers per step,
// 32 steps. XCD M-chunked swizzle.
#define TM 128
#define TN 128
#define TK 32
#define NXCD 8
#define NTILES 512           // (M_/TM)*(N_/TN) = 64*8

__global__ __launch_bounds__(256) void gemm_bt(
    const __hip_bfloat16* __restrict__ A,   // [M_][KC]
    const __hip_bfloat16* __restrict__ B,   // [N_][KC]
    float* __restrict__ P)                  // [M_][N_]
{
    __shared__ __hip_bfloat16 Ah[TM * TK];  // 8 KB each
    __shared__ __hip_bfloat16 Al[TM * TK];
    __shared__ __hip_bfloat16 Bh[TN * TK];
    __shared__ __hip_bfloat16 Bl[TN * TK];

    // XCD M-chunked swizzle: XCD k owns M-panels [8k,8k+8) x all 8 N-panels.
    const int bid  = blockIdx.x;
    const int xcd  = bid & (NXCD - 1);
    const int slot = bid >> 3;
    const int tile = xcd * (NTILES / NXCD) + slot;
    const int ty   = tile >> 3;
    const int tx   = tile & 7;

    const int t    = threadIdx.x;
    const int lane = t & 63;
    const int wv   = t >> 6;
    const int wr   = wv >> 1;
    const int wc   = wv & 1;
    const int m0   = ty * TM;
    const int n0   = tx * TN;
    const int fr   = lane & 15;
    const int kb   = (lane >> 4) << 3;

    floatx4 acc[4][4] = {};

    for (int kt = 0; kt < K_ / TK; ++kt) {     // 32 steps
        const int hi0 = kt * TK;               // hi cols
        const int lo0 = 1024 + kt * TK;        // lo cols
        __syncthreads();   // prior iteration's ds_reads done before overwrite
#pragma unroll
        for (int i = 0; i < 2; ++i) {
            const int chunk = i * 256 + t;     // 0..511, 16B each
            const int row = chunk >> 2;
            const int c8  = (chunk & 3) << 3;
            const size_t arow = (size_t)(m0 + row) * KC;
            const size_t brow = (size_t)(n0 + row) * KC;
            __builtin_amdgcn_global_load_lds(
                (__attribute__((address_space(1))) void*)(A + arow + hi0 + c8),
                (__attribute__((address_space(3))) void*)(&Ah[chunk * 8]), 16, 0, 0);
            __builtin_amdgcn_global_load_lds(
                (__attribute__((address_space(1))) void*)(A + arow + lo0 + c8),
                (__attribute__((address_space(3))) void*)(&Al[chunk * 8]), 16, 0, 0);
            __builtin_amdgcn_global_load_lds(
                (__attribute__((address_space(1))) void*)(B + brow + hi0 + c8),
                (__attribute__((address_space(3))) void*)(&Bh[chunk * 8]), 16, 0, 0);
            __builtin_amdgcn_global_load_lds(
                (__attribute__((address_space(1))) void*)(B + brow + lo0 + c8),
                (__attribute__((address_space(3))) void*)(&Bl[chunk * 8]), 16, 0, 0);
        }
        __syncthreads();   // compiler drains vmcnt before barrier

        short8 afh[4], afl[4], bfh[4], bfl[4];
#pragma unroll
        for (int i = 0; i < 4; ++i) {
            const int ar = (wr * 64 + i * 16 + fr) * TK + kb;
            afh[i] = *reinterpret_cast<const short8*>(&Ah[ar]);
            afl[i] = *reinterpret_cast<const short8*>(&Al[ar]);
        }
#pragma unroll
        for (int j = 0; j < 4; ++j) {
            const int br = (wc * 64 + j * 16 + fr) * TK + kb;
            bfh[j] = *reinterpret_cast<const short8*>(&Bh[br]);
            bfl[j] = *reinterpret_cast<const short8*>(&Bl[br]);
        }
#pragma unroll
        for (int i = 0; i < 4; ++i)
#pragma unroll
            for (int j = 0; j < 4; ++j) {
                acc[i][j] = __builtin_amdgcn_mfma_f32_16x16x32_bf16(afh[i], bfh[j], acc[i][j], 0, 0, 0);
                acc[i][j] = __builtin_amdgcn_mfma_f32_16x16x32_bf16(afl[i], bfh[j], acc[i][j], 0, 0, 0);
                acc[i][j] = __builtin_amdgcn_mfma_f32_16x16x32_bf16(afh[i], bfl[j], acc[i][j], 0, 0, 0);
            }
    }

    // epilogue: C/D layout (16x16): col = lane&15, row = (lane>>4)*4 + reg
#pragma unroll
    for (int j = 0; j < 4; ++j) {
        const int col = n0 + wc * 64 + j * 16 + fr;
#pragma unroll
        for (int i = 0; i < 4; ++i) {
            const int row = m0 + wr * 64 + i * 16 + ((lane >> 4) << 2);
#pragma unroll
            for (int jj = 0; jj < 4; ++jj)
                P[(size_t)(row + jj) * N_ + col] = acc[i][j][jj];
        }
    }
}

// ---------------- sequential scan over S (adds bias) ----------------
// Software-pipelined: prefetch the next NB-step batch of lin into registers
// while processing the current batch. NB=32 -> 32768 thr x 32 x 4B = 4 MB
// in flight >= BW-latency product (~3.8 MB) -> near-peak streaming.
// LAYER==0: emit compact [hi|lo] split activations + h0T.
// LAYER==1: rewrite lin in place with y1 + h1T.
#define NB 32

template <int LAYER>
__global__ __launch_bounds__(64) void scan_k(
    float* lin,                              // [SEQ][BATCH][N_]; LAYER==1: also output
    const float* __restrict__ bias,          // [N_]
    const float* __restrict__ rec,           // [2][N_]
    __hip_bfloat16* __restrict__ asplit,     // LAYER==0: [M_][KC]
    float* __restrict__ hT)                  // [BATCH][2*N_]
{
    const int tid = blockIdx.x * 64 + threadIdx.x;   // 0..32767
    const int b = tid >> 10, n = tid & 1023;
    const float r  = rec[LAYER * N_ + n];
    const float bj = bias[n];
    float h = 0.f;

    float v[NB], vn[NB];
#pragma unroll
    for (int j = 0; j < NB; ++j)
        v[j] = lin[(size_t)j * (BATCH * N_) + tid];

    for (int sb = 0; sb < SEQ / NB; ++sb) {
        const int sbase = sb * NB;
        if (sb + 1 < SEQ / NB) {
#pragma unroll
            for (int j = 0; j < NB; ++j)
                vn[j] = lin[(size_t)(sbase + NB + j) * (BATCH * N_) + tid];
        }
#pragma unroll
        for (int j = 0; j < NB; ++j) {
            h = fmaxf(fmaf(r, h, v[j] + bj), 0.f);
            if (LAYER == 0) {
                const size_t base = (size_t)((sbase + j) * BATCH + b) * KC + n;
                __hip_bfloat16 hi = __float2bfloat16(h);
                __hip_bfloat16 lo = __float2bfloat16(h - __bfloat162float(hi));
                asplit[base]        = hi;   // compact [hi | lo]
                asplit[base + 1024] = lo;
            } else {
                lin[(size_t)(sbase + j) * (BATCH * N_) + tid] = h;
            }
        }
#pragma unroll
        for (int j = 0; j < NB; ++j) v[j] = vn[j];
    }
    hT[(size_t)b * (2 * N_) + LAYER * N_ + n] = h;
}

// ---------------- launch ----------------
extern "C" void kernel_launch(void* const* d_in, const int* in_sizes, int n_in,
                              void* d_out, int out_size, void* d_ws, size_t ws_size,
                              hipStream_t stream)
{
    const float* x   = (const float*)d_in[0];
    const float* w0  = (const float*)d_in[1];
    const float* b0  = (const float*)d_in[2];
    const float* w1  = (const float*)d_in[3];
    const float* b1  = (const float*)d_in[4];
    const float* rec = (const float*)d_in[5];

    float* out = (float*)d_out;
    float* y   = out;                               // [SEQ][BATCH][N_] — lin scratch then final y1
    float* hT  = out + (size_t)SEQ * BATCH * N_;    // [BATCH][2*N_]

    // ws layout: A0 33.55 MB | W0 4.19 MB | W1 4.19 MB  (~42 MB, ws proven >= 63 MB)
    __hip_bfloat16* A0 = (__hip_bfloat16*)d_ws;
    __hip_bfloat16* W0 = A0 + (size_t)M_ * KC;
    __hip_bfloat16* W1 = W0 + (size_t)N_ * KC;

    // 1. split x, w0, w1 -> compact [hi|lo] bf16 (one kernel)
    split_all_k<<<10240, 256, 0, stream>>>(x, A0, w0, W0, w1, W1);

    // 2. lin0 = x @ w0^T   (bias added in scan)
    gemm_bt<<<NTILES, 256, 0, stream>>>(A0, W0, y);

    // 3. scan layer 0 -> compact split acts (reuse A0) + h0T
    scan_k<0><<<(BATCH * N_) / 64, 64, 0, stream>>>(y, b0, rec, A0, hT);

    // 4. lin1 = y0 @ w1^T
    gemm_bt<<<NTILES, 256, 0, stream>>>(A0, W1, y);

    // 5. scan layer 1 -> y1 (in place) + h1T
    scan_k<1><<<(BATCH * N_) / 64, 64, 0, stream>>>(y, b1, rec, nullptr, hT);
}